// Round 2
// baseline (98.622 us; speedup 1.0000x reference)
//
#include <hip/hip_runtime.h>
#include <cstddef>

#define NSLOT 128
#define ALPHA 0.5f
#define B1 0.6931471805599453f   /* log(2)   */
#define B2 0.4054651081081644f   /* log(1.5) */

__device__ __forceinline__ float lrelu(float v) { return v >= 0.0f ? v : 0.01f * v; }

// Stage a 64-graph chunk (36 floats/graph) via coalesced float4 loads into the
// wave's LDS region (576 float4 slots, XOR-swizzled), then read this lane's
// graph into dst[36]. Wave-synchronous: no __syncthreads.
__device__ __forceinline__ void stage36(const float* __restrict__ gsrc,
                                        float4* __restrict__ bufw,
                                        int lane, int gcount, float dst[36]) {
  const int nf4 = gcount * 9;
#pragma unroll
  for (int k = 0; k < 9; ++k) {
    const int F = k * 64 + lane;          // linear float4 index in stream
    if (F < nf4) {
      float4 v = reinterpret_cast<const float4*>(gsrc)[F];
      const int g = F / 9;                // graph this float4 belongs to
      bufw[F ^ ((g >> 3) & 7)] = v;       // swizzled store (bijective)
    }
  }
  // same-wave DS ops are in-order; fence data visibility + stop reordering
  __asm__ volatile("s_waitcnt lgkmcnt(0)" ::: "memory");
  __builtin_amdgcn_sched_barrier(0);
  if (lane < gcount) {
    const int s = (lane >> 3) & 7;
#pragma unroll
    for (int j = 0; j < 9; ++j) {
      float4 v = bufw[(lane * 9 + j) ^ s];
      dst[4 * j + 0] = v.x; dst[4 * j + 1] = v.y;
      dst[4 * j + 2] = v.z; dst[4 * j + 3] = v.w;
    }
  }
  __asm__ volatile("s_waitcnt lgkmcnt(0)" ::: "memory");
  __builtin_amdgcn_sched_barrier(0);
}

// Two GCN2Conv layers for one graph; xv/w in registers, lw = W1,b1,W2,b2.
__device__ __forceinline__ void compute_h2(float xv[36], const float w[36],
                                           const float* __restrict__ lw,
                                           float h2[36]) {
  float t[36];
  const float* W1  = lw;
  const float* bb1 = lw + 36;
  const float* W2  = lw + 42;
  const float* bb2 = lw + 78;
#pragma unroll
  for (int j = 0; j < 6; ++j)
#pragma unroll
    for (int f = 0; f < 6; ++f) {
      float a = 0.0f;
#pragma unroll
      for (int i = 0; i < 6; ++i) a = fmaf(w[i * 6 + j], xv[i * 6 + f], a);
      t[j * 6 + f] = ALPHA * (a * (1.0f / 6.0f)) + ALPHA * xv[j * 6 + f];
    }
#pragma unroll
  for (int j = 0; j < 6; ++j)
#pragma unroll
    for (int f = 0; f < 6; ++f) {
      float a = 0.0f;
#pragma unroll
      for (int k = 0; k < 6; ++k) a = fmaf(t[j * 6 + k], W1[k * 6 + f], a);
      xv[j * 6 + f] = lrelu((1.0f - B1) * t[j * 6 + f] + B1 * a + bb1[f]);
    }
#pragma unroll
  for (int j = 0; j < 6; ++j)
#pragma unroll
    for (int f = 0; f < 6; ++f) {
      float a = 0.0f;
#pragma unroll
      for (int i = 0; i < 6; ++i) a = fmaf(w[i * 6 + j], xv[i * 6 + f], a);
      t[j * 6 + f] = ALPHA * (a * (1.0f / 6.0f)) + ALPHA * xv[j * 6 + f];
    }
#pragma unroll
  for (int j = 0; j < 6; ++j)
#pragma unroll
    for (int f = 0; f < 6; ++f) {
      float a = 0.0f;
#pragma unroll
      for (int k = 0; k < 6; ++k) a = fmaf(t[j * 6 + k], W2[k * 6 + f], a);
      h2[j * 6 + f] = (1.0f - B2) * t[j * 6 + f] + B2 * a + bb2[f];
    }
}

__global__ __launch_bounds__(256) void gcn2_pass1(
    const float* __restrict__ x, const float* __restrict__ ew,
    const float* __restrict__ W1, const float* __restrict__ b1,
    const float* __restrict__ W2, const float* __restrict__ b2,
    float* __restrict__ wsred, int G) {
  __shared__ float lw[84];
  __shared__ float4 buf[4 * 576];
  const int tid = threadIdx.x;
  if (tid < 84) {
    float v;
    if (tid < 36)      v = W1[tid];
    else if (tid < 42) v = b1[tid - 36];
    else if (tid < 78) v = W2[tid - 42];
    else               v = b2[tid - 78];
    lw[tid] = v;
  }
  __syncthreads();

  const int lane = tid & 63;
  const int wid  = tid >> 6;
  float4* bufw = buf + wid * 576;
  const int wg0 = blockIdx.x * 256 + wid * 64;   // first graph of this wave
  int gcount = G - wg0;
  gcount = gcount < 0 ? 0 : (gcount > 64 ? 64 : gcount);

  float xv[36], w[36];
  stage36(x  + (size_t)wg0 * 36, bufw, lane, gcount, xv);
  stage36(ew + (size_t)wg0 * 36, bufw, lane, gcount, w);

  float s[6]  = {0.f, 0.f, 0.f, 0.f, 0.f, 0.f};
  float ss[6] = {0.f, 0.f, 0.f, 0.f, 0.f, 0.f};
  if (lane < gcount) {
    float h2[36];
    compute_h2(xv, w, lw, h2);
#pragma unroll
    for (int f = 0; f < 6; ++f)
#pragma unroll
      for (int j = 0; j < 6; ++j) {
        float v = h2[j * 6 + f];
        s[f] += v;
        ss[f] = fmaf(v, v, ss[f]);
      }
  }
#pragma unroll
  for (int f = 0; f < 6; ++f)
#pragma unroll
    for (int o = 32; o >= 1; o >>= 1) {
      s[f]  += __shfl_down(s[f],  (unsigned)o, 64);
      ss[f] += __shfl_down(ss[f], (unsigned)o, 64);
    }
  if (lane == 0) {
    const int wgid = blockIdx.x * 4 + wid;
    float* p = wsred + (size_t)(wgid & (NSLOT - 1)) * 12;
#pragma unroll
    for (int f = 0; f < 6; ++f) {
      atomicAdd(p + f,     s[f]);
      atomicAdd(p + 6 + f, ss[f]);
    }
  }
}

__global__ void gcn2_finalize(const float* __restrict__ wsred,
                              const float* __restrict__ gamma,
                              const float* __restrict__ beta_bn,
                              float* __restrict__ stats, float invN) {
  __shared__ float tot[12];
  const int t = threadIdx.x;
  if (t < 12) {
    float a = 0.0f;
    for (int sIdx = 0; sIdx < NSLOT; ++sIdx) a += wsred[sIdx * 12 + t];
    tot[t] = a;
  }
  __syncthreads();
  if (t < 6) {
    float mean = tot[t] * invN;
    float var  = tot[6 + t] * invN - mean * mean;
    float istd = rsqrtf(var + 1e-5f);
    float sc   = istd * gamma[t];
    stats[t]     = sc;
    stats[6 + t] = beta_bn[t] - mean * sc;
  }
}

__global__ __launch_bounds__(256) void gcn2_pass2(
    const float* __restrict__ x, const float* __restrict__ ew,
    const float* __restrict__ W1, const float* __restrict__ b1,
    const float* __restrict__ W2, const float* __restrict__ b2,
    const float* __restrict__ fcW1, const float* __restrict__ fcb1,
    const float* __restrict__ fcW2, const float* __restrict__ fcb2,
    const float* __restrict__ stats, float* __restrict__ out, int G) {
  __shared__ float lw[188];
  __shared__ float4 buf[4 * 576];
  const int tid = threadIdx.x;
  if (tid < 188) {
    float v;
    if (tid < 36)       v = W1[tid];
    else if (tid < 42)  v = b1[tid - 36];
    else if (tid < 78)  v = W2[tid - 42];
    else if (tid < 84)  v = b2[tid - 78];
    else if (tid < 144) v = fcW1[tid - 84];
    else if (tid < 154) v = fcb1[tid - 144];
    else if (tid < 174) v = fcW2[tid - 154];
    else if (tid < 176) v = fcb2[tid - 174];
    else                v = stats[tid - 176];
    lw[tid] = v;
  }
  __syncthreads();

  const int lane = tid & 63;
  const int wid  = tid >> 6;
  float4* bufw = buf + wid * 576;
  const int wg0 = blockIdx.x * 256 + wid * 64;
  int gcount = G - wg0;
  gcount = gcount < 0 ? 0 : (gcount > 64 ? 64 : gcount);

  float xv[36], w[36];
  stage36(x  + (size_t)wg0 * 36, bufw, lane, gcount, xv);
  stage36(ew + (size_t)wg0 * 36, bufw, lane, gcount, w);

  if (lane >= gcount) return;

  float h2[36];
  compute_h2(xv, w, lw, h2);

  const float* scale = lw + 176;
  const float* shift = lw + 182;
  float pooled[6] = {0.f, 0.f, 0.f, 0.f, 0.f, 0.f};
#pragma unroll
  for (int j = 0; j < 6; ++j)
#pragma unroll
    for (int f = 0; f < 6; ++f)
      pooled[f] += lrelu(fmaf(h2[j * 6 + f], scale[f], shift[f]));

  const float* fw1 = lw + 84;
  const float* fb1 = lw + 144;
  const float* fw2 = lw + 154;
  const float* fb2 = lw + 174;
  float p1[10];
#pragma unroll
  for (int m = 0; m < 10; ++m) {
    float a = fb1[m];
#pragma unroll
    for (int f = 0; f < 6; ++f) a = fmaf(pooled[f], fw1[f * 10 + m], a);
    p1[m] = lrelu(a);
  }
  float o0 = fb2[0], o1 = fb2[1];
#pragma unroll
  for (int m = 0; m < 10; ++m) {
    o0 = fmaf(p1[m], fw2[m * 2 + 0], o0);
    o1 = fmaf(p1[m], fw2[m * 2 + 1], o1);
  }
  const int g = wg0 + lane;
  reinterpret_cast<float2*>(out)[g] = make_float2(o0, o1);
}

extern "C" void kernel_launch(void* const* d_in, const int* in_sizes, int n_in,
                              void* d_out, int out_size, void* d_ws, size_t ws_size,
                              hipStream_t stream) {
  const float* x     = (const float*)d_in[0];
  const float* ew    = (const float*)d_in[1];
  const float* W1    = (const float*)d_in[2];
  const float* b1    = (const float*)d_in[3];
  const float* W2    = (const float*)d_in[4];
  const float* b2    = (const float*)d_in[5];
  const float* gamma = (const float*)d_in[6];
  const float* beta  = (const float*)d_in[7];
  const float* fcW1  = (const float*)d_in[8];
  const float* fcb1  = (const float*)d_in[9];
  const float* fcW2  = (const float*)d_in[10];
  const float* fcb2  = (const float*)d_in[11];

  const int G = in_sizes[0] / 36;

  float* wsred = (float*)d_ws;
  float* stats = wsred + NSLOT * 12;

  hipMemsetAsync(d_ws, 0, NSLOT * 12 * sizeof(float), stream);

  const int block = 256;
  const int grid  = (G + block - 1) / block;
  gcn2_pass1<<<grid, block, 0, stream>>>(x, ew, W1, b1, W2, b2, wsred, G);
  gcn2_finalize<<<1, 64, 0, stream>>>(wsred, gamma, beta,
                                      stats, 1.0f / (6.0f * (float)G));
  gcn2_pass2<<<grid, block, 0, stream>>>(x, ew, W1, b1, W2, b2,
                                         fcW1, fcb1, fcW2, fcb2,
                                         stats, (float*)d_out, G);
}

// Round 3
// 90.318 us; speedup vs baseline: 1.0919x; 1.0919x over previous
//
#include <hip/hip_runtime.h>
#include <cstddef>

#define NSLOT 128
#define ALPHA 0.5f
#define B1 0.6931471805599453f   /* log(2)   */
#define B2 0.4054651081081644f   /* log(1.5) */

__device__ __forceinline__ float lrelu(float v) { return v >= 0.0f ? v : 0.01f * v; }

// Two GCN2Conv layers for one graph; xv/w in registers, lw = W1,b1,W2,b2.
__device__ __forceinline__ void compute_h2(float xv[36], const float w[36],
                                           const float* __restrict__ lw,
                                           float h2[36]) {
  float t[36];
  const float* W1  = lw;
  const float* bb1 = lw + 36;
  const float* W2  = lw + 42;
  const float* bb2 = lw + 78;
#pragma unroll
  for (int j = 0; j < 6; ++j)
#pragma unroll
    for (int f = 0; f < 6; ++f) {
      float a = 0.0f;
#pragma unroll
      for (int i = 0; i < 6; ++i) a = fmaf(w[i * 6 + j], xv[i * 6 + f], a);
      t[j * 6 + f] = ALPHA * (a * (1.0f / 6.0f)) + ALPHA * xv[j * 6 + f];
    }
#pragma unroll
  for (int j = 0; j < 6; ++j)
#pragma unroll
    for (int f = 0; f < 6; ++f) {
      float a = 0.0f;
#pragma unroll
      for (int k = 0; k < 6; ++k) a = fmaf(t[j * 6 + k], W1[k * 6 + f], a);
      xv[j * 6 + f] = lrelu((1.0f - B1) * t[j * 6 + f] + B1 * a + bb1[f]);
    }
#pragma unroll
  for (int j = 0; j < 6; ++j)
#pragma unroll
    for (int f = 0; f < 6; ++f) {
      float a = 0.0f;
#pragma unroll
      for (int i = 0; i < 6; ++i) a = fmaf(w[i * 6 + j], xv[i * 6 + f], a);
      t[j * 6 + f] = ALPHA * (a * (1.0f / 6.0f)) + ALPHA * xv[j * 6 + f];
    }
#pragma unroll
  for (int j = 0; j < 6; ++j)
#pragma unroll
    for (int f = 0; f < 6; ++f) {
      float a = 0.0f;
#pragma unroll
      for (int k = 0; k < 6; ++k) a = fmaf(t[j * 6 + k], W2[k * 6 + f], a);
      h2[j * 6 + f] = (1.0f - B2) * t[j * 6 + f] + B2 * a + bb2[f];
    }
}

// Deep-pipelined wave-local stage: ALL 18 global loads in flight before the
// single LDS fence. xb/wb are this wave's private 576-float4 regions.
__device__ __forceinline__ void stage_both(const float4* __restrict__ gx,
                                           const float4* __restrict__ gw,
                                           float4* __restrict__ xb,
                                           float4* __restrict__ wb,
                                           int lane, int gcount,
                                           float xv[36], float w[36]) {
  float4 tx[9], tw[9];
  if (gcount == 64) {
#pragma unroll
    for (int k = 0; k < 9; ++k) tx[k] = gx[k * 64 + lane];
#pragma unroll
    for (int k = 0; k < 9; ++k) tw[k] = gw[k * 64 + lane];
  } else {
    const int nf4 = gcount * 9;
#pragma unroll
    for (int k = 0; k < 9; ++k) {
      const int F = k * 64 + lane;
      tx[k] = (F < nf4) ? gx[F] : make_float4(0.f, 0.f, 0.f, 0.f);
    }
#pragma unroll
    for (int k = 0; k < 9; ++k) {
      const int F = k * 64 + lane;
      tw[k] = (F < nf4) ? gw[F] : make_float4(0.f, 0.f, 0.f, 0.f);
    }
  }
#pragma unroll
  for (int k = 0; k < 9; ++k) xb[k * 64 + lane] = tx[k];
#pragma unroll
  for (int k = 0; k < 9; ++k) wb[k * 64 + lane] = tw[k];
  // single fence: same-wave DS ops are in-order; just drain before reads
  __asm__ volatile("s_waitcnt lgkmcnt(0)" ::: "memory");
  __builtin_amdgcn_sched_barrier(0);
  if (lane < gcount) {
#pragma unroll
    for (int j = 0; j < 9; ++j) {
      float4 v = xb[lane * 9 + j];
      xv[4 * j + 0] = v.x; xv[4 * j + 1] = v.y;
      xv[4 * j + 2] = v.z; xv[4 * j + 3] = v.w;
    }
#pragma unroll
    for (int j = 0; j < 9; ++j) {
      float4 v = wb[lane * 9 + j];
      w[4 * j + 0] = v.x; w[4 * j + 1] = v.y;
      w[4 * j + 2] = v.z; w[4 * j + 3] = v.w;
    }
  }
}

__global__ __launch_bounds__(256) void gcn2_pass1(
    const float* __restrict__ x, const float* __restrict__ ew,
    const float* __restrict__ W1, const float* __restrict__ b1,
    const float* __restrict__ W2, const float* __restrict__ b2,
    float* __restrict__ wsred, int G) {
  __shared__ float lw[84];
  __shared__ float4 xbuf[4 * 576];
  __shared__ float4 wbuf[4 * 576];
  const int tid = threadIdx.x;
  if (tid < 84) {
    float v;
    if (tid < 36)      v = W1[tid];
    else if (tid < 42) v = b1[tid - 36];
    else if (tid < 78) v = W2[tid - 42];
    else               v = b2[tid - 78];
    lw[tid] = v;
  }
  __syncthreads();

  const int lane = tid & 63;
  const int wid  = tid >> 6;
  const int wg0  = blockIdx.x * 256 + wid * 64;
  int gcount = G - wg0;
  gcount = gcount < 0 ? 0 : (gcount > 64 ? 64 : gcount);

  float xv[36], w[36];
  stage_both(reinterpret_cast<const float4*>(x + (size_t)wg0 * 36),
             reinterpret_cast<const float4*>(ew + (size_t)wg0 * 36),
             xbuf + wid * 576, wbuf + wid * 576, lane, gcount, xv, w);

  float s[6]  = {0.f, 0.f, 0.f, 0.f, 0.f, 0.f};
  float ss[6] = {0.f, 0.f, 0.f, 0.f, 0.f, 0.f};
  if (lane < gcount) {
    float h2[36];
    compute_h2(xv, w, lw, h2);
#pragma unroll
    for (int f = 0; f < 6; ++f)
#pragma unroll
      for (int j = 0; j < 6; ++j) {
        float v = h2[j * 6 + f];
        s[f] += v;
        ss[f] = fmaf(v, v, ss[f]);
      }
  }
#pragma unroll
  for (int f = 0; f < 6; ++f)
#pragma unroll
    for (int o = 32; o >= 1; o >>= 1) {
      s[f]  += __shfl_down(s[f],  (unsigned)o, 64);
      ss[f] += __shfl_down(ss[f], (unsigned)o, 64);
    }
  if (lane == 0) {
    const int wgid = blockIdx.x * 4 + wid;
    float* p = wsred + (size_t)(wgid & (NSLOT - 1)) * 12;
#pragma unroll
    for (int f = 0; f < 6; ++f) {
      atomicAdd(p + f,     s[f]);
      atomicAdd(p + 6 + f, ss[f]);
    }
  }
}

__global__ __launch_bounds__(256) void gcn2_pass2(
    const float* __restrict__ x, const float* __restrict__ ew,
    const float* __restrict__ W1, const float* __restrict__ b1,
    const float* __restrict__ W2, const float* __restrict__ b2,
    const float* __restrict__ fcW1, const float* __restrict__ fcb1,
    const float* __restrict__ fcW2, const float* __restrict__ fcb2,
    const float* __restrict__ gamma, const float* __restrict__ beta_bn,
    const float* __restrict__ wsred, float invN,
    float* __restrict__ out, int G) {
  // lw: [0..83] conv, [84..143] fcW1, [144..153] fcb1, [154..173] fcW2,
  //     [174..175] fcb2, [176..181] scale, [182..187] shift
  __shared__ float lw[188];
  __shared__ float sstat[12];
  __shared__ float4 xbuf[4 * 576];
  __shared__ float4 wbuf[4 * 576];
  const int tid = threadIdx.x;
  if (tid < 176) {
    float v;
    if (tid < 36)       v = W1[tid];
    else if (tid < 42)  v = b1[tid - 36];
    else if (tid < 78)  v = W2[tid - 42];
    else if (tid < 84)  v = b2[tid - 78];
    else if (tid < 144) v = fcW1[tid - 84];
    else if (tid < 154) v = fcb1[tid - 144];
    else if (tid < 174) v = fcW2[tid - 154];
    else                v = fcb2[tid - 174];
    lw[tid] = v;
  } else if (tid >= 192 && tid < 204) {
    const int t = tid - 192;
    float a = 0.0f;
#pragma unroll 8
    for (int sIdx = 0; sIdx < NSLOT; ++sIdx) a += wsred[sIdx * 12 + t];
    sstat[t] = a;
  }
  __syncthreads();
  if (tid < 6) {
    float mean = sstat[tid] * invN;
    float var  = sstat[6 + tid] * invN - mean * mean;
    float sc   = rsqrtf(var + 1e-5f) * gamma[tid];
    lw[176 + tid] = sc;
    lw[182 + tid] = beta_bn[tid] - mean * sc;
  }
  __syncthreads();

  const int lane = tid & 63;
  const int wid  = tid >> 6;
  const int wg0  = blockIdx.x * 256 + wid * 64;
  int gcount = G - wg0;
  gcount = gcount < 0 ? 0 : (gcount > 64 ? 64 : gcount);

  float xv[36], w[36];
  stage_both(reinterpret_cast<const float4*>(x + (size_t)wg0 * 36),
             reinterpret_cast<const float4*>(ew + (size_t)wg0 * 36),
             xbuf + wid * 576, wbuf + wid * 576, lane, gcount, xv, w);

  if (lane >= gcount) return;

  float h2[36];
  compute_h2(xv, w, lw, h2);

  const float* scale = lw + 176;
  const float* shift = lw + 182;
  float pooled[6] = {0.f, 0.f, 0.f, 0.f, 0.f, 0.f};
#pragma unroll
  for (int j = 0; j < 6; ++j)
#pragma unroll
    for (int f = 0; f < 6; ++f)
      pooled[f] += lrelu(fmaf(h2[j * 6 + f], scale[f], shift[f]));

  const float* fw1 = lw + 84;
  const float* fb1 = lw + 144;
  const float* fw2 = lw + 154;
  const float* fb2 = lw + 174;
  float p1[10];
#pragma unroll
  for (int m = 0; m < 10; ++m) {
    float a = fb1[m];
#pragma unroll
    for (int f = 0; f < 6; ++f) a = fmaf(pooled[f], fw1[f * 10 + m], a);
    p1[m] = lrelu(a);
  }
  float o0 = fb2[0], o1 = fb2[1];
#pragma unroll
  for (int m = 0; m < 10; ++m) {
    o0 = fmaf(p1[m], fw2[m * 2 + 0], o0);
    o1 = fmaf(p1[m], fw2[m * 2 + 1], o1);
  }
  reinterpret_cast<float2*>(out)[wg0 + lane] = make_float2(o0, o1);
}

extern "C" void kernel_launch(void* const* d_in, const int* in_sizes, int n_in,
                              void* d_out, int out_size, void* d_ws, size_t ws_size,
                              hipStream_t stream) {
  const float* x     = (const float*)d_in[0];
  const float* ew    = (const float*)d_in[1];
  const float* W1    = (const float*)d_in[2];
  const float* b1    = (const float*)d_in[3];
  const float* W2    = (const float*)d_in[4];
  const float* b2    = (const float*)d_in[5];
  const float* gamma = (const float*)d_in[6];
  const float* beta  = (const float*)d_in[7];
  const float* fcW1  = (const float*)d_in[8];
  const float* fcb1  = (const float*)d_in[9];
  const float* fcW2  = (const float*)d_in[10];
  const float* fcb2  = (const float*)d_in[11];

  const int G = in_sizes[0] / 36;

  float* wsred = (float*)d_ws;
  hipMemsetAsync(d_ws, 0, NSLOT * 12 * sizeof(float), stream);

  const int block = 256;
  const int grid  = (G + block - 1) / block;
  gcn2_pass1<<<grid, block, 0, stream>>>(x, ew, W1, b1, W2, b2, wsred, G);
  gcn2_pass2<<<grid, block, 0, stream>>>(x, ew, W1, b1, W2, b2,
                                         fcW1, fcb1, fcW2, fcb2,
                                         gamma, beta, wsred,
                                         1.0f / (6.0f * (float)G),
                                         (float*)d_out, G);
}

// Round 4
// 71.686 us; speedup vs baseline: 1.3758x; 1.2599x over previous
//
#include <hip/hip_runtime.h>
#include <cstddef>

#define NSLOT 64
#define ALPHA 0.5f
#define B1f 0.6931471805599453f   /* log(2)   */
#define B2f 0.4054651081081644f   /* log(1.5) */

__device__ __forceinline__ float lrelu(float v) { return v >= 0.0f ? v : 0.01f * v; }

// component extract with compile-time index (folds after unrolling)
__device__ __forceinline__ float gc(const float4* a, int idx) {
  const float4 v = a[idx >> 2];
  const int c = idx & 3;
  return c == 0 ? v.x : (c == 1 ? v.y : (c == 2 ? v.z : v.w));
}

// Issue the 18 float4 loads for this lane's graph of chunk `ch`.
__device__ __forceinline__ void load_chunk(const float* __restrict__ x,
                                           const float* __restrict__ ew,
                                           int ch, int G, int lane,
                                           float4 X[9], float4 W[9]) {
  int g = ch * 64 + lane;
  if (g > G - 1) g = G - 1;            // clamp: stay in bounds, result masked later
  const float4* px = reinterpret_cast<const float4*>(x) + (size_t)g * 9;
  const float4* pw = reinterpret_cast<const float4*>(ew) + (size_t)g * 9;
#pragma unroll
  for (int k = 0; k < 9; ++k) X[k] = px[k];
#pragma unroll
  for (int k = 0; k < 9; ++k) W[k] = pw[k];
}

// Two GCN2Conv layers for one graph. Weights via uniform scalar loads.
__device__ __forceinline__ void compute_h2(const float4 X[9], const float4 Wt[9],
                                           const float* __restrict__ gW1,
                                           const float* __restrict__ gb1,
                                           const float* __restrict__ gW2,
                                           const float* __restrict__ gb2,
                                           float h2[36]) {
  float t[36];
#pragma unroll
  for (int j = 0; j < 6; ++j)
#pragma unroll
    for (int f = 0; f < 6; ++f) {
      float a = 0.f;
#pragma unroll
      for (int i = 0; i < 6; ++i) a = fmaf(gc(Wt, i * 6 + j), gc(X, i * 6 + f), a);
      t[j * 6 + f] = fmaf(a, ALPHA * (1.f / 6.f), ALPHA * gc(X, j * 6 + f));
    }
  float h1[36];
#pragma unroll
  for (int j = 0; j < 6; ++j)
#pragma unroll
    for (int f = 0; f < 6; ++f) {
      float a = 0.f;
#pragma unroll
      for (int k = 0; k < 6; ++k) a = fmaf(t[j * 6 + k], gW1[k * 6 + f], a);
      h1[j * 6 + f] = lrelu(fmaf(B1f, a, fmaf(1.f - B1f, t[j * 6 + f], gb1[f])));
    }
#pragma unroll
  for (int j = 0; j < 6; ++j)
#pragma unroll
    for (int f = 0; f < 6; ++f) {
      float a = 0.f;
#pragma unroll
      for (int i = 0; i < 6; ++i) a = fmaf(gc(Wt, i * 6 + j), h1[i * 6 + f], a);
      t[j * 6 + f] = fmaf(a, ALPHA * (1.f / 6.f), ALPHA * h1[j * 6 + f]);
    }
#pragma unroll
  for (int j = 0; j < 6; ++j)
#pragma unroll
    for (int f = 0; f < 6; ++f) {
      float a = 0.f;
#pragma unroll
      for (int k = 0; k < 6; ++k) a = fmaf(t[j * 6 + k], gW2[k * 6 + f], a);
      h2[j * 6 + f] = fmaf(B2f, a, fmaf(1.f - B2f, t[j * 6 + f], gb2[f]));
    }
}

__device__ __forceinline__ void accum_stats(const float h2[36], bool valid,
                                            float s[6], float ss[6]) {
  if (!valid) return;
#pragma unroll
  for (int f = 0; f < 6; ++f)
#pragma unroll
    for (int j = 0; j < 6; ++j) {
      float v = h2[j * 6 + f];
      s[f] += v;
      ss[f] = fmaf(v, v, ss[f]);
    }
}

__global__ __launch_bounds__(256) void gcn2_pass1(
    const float* __restrict__ x, const float* __restrict__ ew,
    const float* __restrict__ gW1, const float* __restrict__ gb1,
    const float* __restrict__ gW2, const float* __restrict__ gb2,
    float* __restrict__ wsred, int G) {
  const int tid  = threadIdx.x;
  const int lane = tid & 63;
  const int wid  = blockIdx.x * 4 + (tid >> 6);
  const int wstride = gridDim.x * 4;
  const int nch = (G + 63) >> 6;

  float s[6]  = {0.f, 0.f, 0.f, 0.f, 0.f, 0.f};
  float ss[6] = {0.f, 0.f, 0.f, 0.f, 0.f, 0.f};

  int c = wid;
  if (c < nch) {
    float4 XA[9], WA[9], XB[9], WB[9];
    load_chunk(x, ew, c, G, lane, XA, WA);
    int cn = c + wstride;
    bool hb = cn < nch;
    if (hb) load_chunk(x, ew, cn, G, lane, XB, WB);
    for (;;) {
      {
        float h2[36];
        compute_h2(XA, WA, gW1, gb1, gW2, gb2, h2);
        accum_stats(h2, c * 64 + lane < G, s, ss);
      }
      if (!hb) break;
      c = cn; cn += wstride;
      const bool hc = cn < nch;
      if (hc) load_chunk(x, ew, cn, G, lane, XA, WA);
      {
        float h2[36];
        compute_h2(XB, WB, gW1, gb1, gW2, gb2, h2);
        accum_stats(h2, c * 64 + lane < G, s, ss);
      }
      if (!hc) break;
      c = cn; cn += wstride;
      hb = cn < nch;
      if (hb) load_chunk(x, ew, cn, G, lane, XB, WB);
    }
  }

#pragma unroll
  for (int f = 0; f < 6; ++f)
#pragma unroll
    for (int o = 32; o >= 1; o >>= 1) {
      s[f]  += __shfl_down(s[f],  (unsigned)o, 64);
      ss[f] += __shfl_down(ss[f], (unsigned)o, 64);
    }
  if (lane == 0) {
    float* p = wsred + (size_t)(wid & (NSLOT - 1)) * 12;
#pragma unroll
    for (int f = 0; f < 6; ++f) {
      atomicAdd(p + f,     s[f]);
      atomicAdd(p + 6 + f, ss[f]);
    }
  }
}

__global__ __launch_bounds__(256) void gcn2_pass2(
    const float* __restrict__ x, const float* __restrict__ ew,
    const float* __restrict__ gW1, const float* __restrict__ gb1,
    const float* __restrict__ gW2, const float* __restrict__ gb2,
    const float* __restrict__ fcW1, const float* __restrict__ fcb1,
    const float* __restrict__ fcW2, const float* __restrict__ fcb2,
    const float* __restrict__ gGamma, const float* __restrict__ gBeta,
    const float* __restrict__ wsred, float invN,
    float2* __restrict__ out, int G) {
  const int tid  = threadIdx.x;
  const int lane = tid & 63;
  const int wid  = blockIdx.x * 4 + (tid >> 6);
  const int wstride = gridDim.x * 4;
  const int nch = (G + 63) >> 6;

  // BN finalize, redundantly per wave: lane reads slot `lane`, butterfly-reduce.
  float st[12];
  {
    const float4* p = reinterpret_cast<const float4*>(wsred) + (size_t)lane * 3;
    float4 a = p[0], b = p[1], c4 = p[2];
    st[0] = a.x;  st[1] = a.y;  st[2]  = a.z;  st[3]  = a.w;
    st[4] = b.x;  st[5] = b.y;  st[6]  = b.z;  st[7]  = b.w;
    st[8] = c4.x; st[9] = c4.y; st[10] = c4.z; st[11] = c4.w;
#pragma unroll
    for (int k = 0; k < 12; ++k)
#pragma unroll
      for (int o = 32; o >= 1; o >>= 1) st[k] += __shfl_xor(st[k], (unsigned)o, 64);
  }
  float sc[6], sh[6];
#pragma unroll
  for (int f = 0; f < 6; ++f) {
    float mean = st[f] * invN;
    float var  = st[6 + f] * invN - mean * mean;
    float s    = rsqrtf(var + 1e-5f) * gGamma[f];
    sc[f] = s;
    sh[f] = gBeta[f] - mean * s;
  }

  int c = wid;
  if (c >= nch) return;
  float4 XA[9], WA[9], XB[9], WB[9];
  load_chunk(x, ew, c, G, lane, XA, WA);
  int cn = c + wstride;
  bool hb = cn < nch;
  if (hb) load_chunk(x, ew, cn, G, lane, XB, WB);

  for (;;) {
    {
      float h2[36];
      compute_h2(XA, WA, gW1, gb1, gW2, gb2, h2);
      const int g = c * 64 + lane;
      if (g < G) {
        float pooled[6] = {0.f, 0.f, 0.f, 0.f, 0.f, 0.f};
#pragma unroll
        for (int j = 0; j < 6; ++j)
#pragma unroll
          for (int f = 0; f < 6; ++f)
            pooled[f] += lrelu(fmaf(h2[j * 6 + f], sc[f], sh[f]));
        float p1[10];
#pragma unroll
        for (int m = 0; m < 10; ++m) {
          float a = fcb1[m];
#pragma unroll
          for (int f = 0; f < 6; ++f) a = fmaf(pooled[f], fcW1[f * 10 + m], a);
          p1[m] = lrelu(a);
        }
        float o0 = fcb2[0], o1 = fcb2[1];
#pragma unroll
        for (int m = 0; m < 10; ++m) {
          o0 = fmaf(p1[m], fcW2[m * 2 + 0], o0);
          o1 = fmaf(p1[m], fcW2[m * 2 + 1], o1);
        }
        out[g] = make_float2(o0, o1);
      }
    }
    if (!hb) break;
    c = cn; cn += wstride;
    const bool hc = cn < nch;
    if (hc) load_chunk(x, ew, cn, G, lane, XA, WA);
    {
      float h2[36];
      compute_h2(XB, WB, gW1, gb1, gW2, gb2, h2);
      const int g = c * 64 + lane;
      if (g < G) {
        float pooled[6] = {0.f, 0.f, 0.f, 0.f, 0.f, 0.f};
#pragma unroll
        for (int j = 0; j < 6; ++j)
#pragma unroll
          for (int f = 0; f < 6; ++f)
            pooled[f] += lrelu(fmaf(h2[j * 6 + f], sc[f], sh[f]));
        float p1[10];
#pragma unroll
        for (int m = 0; m < 10; ++m) {
          float a = fcb1[m];
#pragma unroll
          for (int f = 0; f < 6; ++f) a = fmaf(pooled[f], fcW1[f * 10 + m], a);
          p1[m] = lrelu(a);
        }
        float o0 = fcb2[0], o1 = fcb2[1];
#pragma unroll
        for (int m = 0; m < 10; ++m) {
          o0 = fmaf(p1[m], fcW2[m * 2 + 0], o0);
          o1 = fmaf(p1[m], fcW2[m * 2 + 1], o1);
        }
        out[g] = make_float2(o0, o1);
      }
    }
    if (!hc) break;
    c = cn; cn += wstride;
    hb = cn < nch;
    if (hb) load_chunk(x, ew, cn, G, lane, XB, WB);
  }
}

extern "C" void kernel_launch(void* const* d_in, const int* in_sizes, int n_in,
                              void* d_out, int out_size, void* d_ws, size_t ws_size,
                              hipStream_t stream) {
  const float* x     = (const float*)d_in[0];
  const float* ew    = (const float*)d_in[1];
  const float* W1    = (const float*)d_in[2];
  const float* b1    = (const float*)d_in[3];
  const float* W2    = (const float*)d_in[4];
  const float* b2    = (const float*)d_in[5];
  const float* gamma = (const float*)d_in[6];
  const float* beta  = (const float*)d_in[7];
  const float* fcW1  = (const float*)d_in[8];
  const float* fcb1  = (const float*)d_in[9];
  const float* fcW2  = (const float*)d_in[10];
  const float* fcb2  = (const float*)d_in[11];

  const int G   = in_sizes[0] / 36;
  const int nch = (G + 63) / 64;

  float* wsred = (float*)d_ws;
  hipMemsetAsync(d_ws, 0, NSLOT * 12 * sizeof(float), stream);

  int blocks = (nch + 3) / 4;
  if (blocks > 512) blocks = 512;
  if (blocks < 1)   blocks = 1;

  gcn2_pass1<<<blocks, 256, 0, stream>>>(x, ew, W1, b1, W2, b2, wsred, G);
  gcn2_pass2<<<blocks, 256, 0, stream>>>(x, ew, W1, b1, W2, b2,
                                         fcW1, fcb1, fcW2, fcb2,
                                         gamma, beta, wsred,
                                         1.0f / (6.0f * (float)G),
                                         (float2*)d_out, G);
}